// Round 6
// baseline (89.577 us; speedup 1.0000x reference)
//
#include <hip/hip_runtime.h>
#include <hip/hip_bf16.h>
#include <cstdint>
#include <cstddef>

typedef __bf16 bf16_t;
typedef bf16_t bf16x8 __attribute__((ext_vector_type(8)));
typedef float f32x4 __attribute__((ext_vector_type(4)));
typedef float f32x16 __attribute__((ext_vector_type(16)));
typedef unsigned short u16;
typedef u16 u16x8 __attribute__((ext_vector_type(8)));

#define S_LEN 2048
#define NB 2
#define NH 8
#define DHD 64
#define DM 512

static __device__ __forceinline__ u16 bfbits(float f) {
  union { __bf16 h; u16 u; } c; c.h = (__bf16)f; return c.u;
}
static __device__ __forceinline__ float bits2f(u16 b) {
  union { u16 u; __bf16 h; } c; c.u = b; return (float)c.h;
}
static __device__ __forceinline__ uint32_t pkbf(float a, float b) {
  union { __bf16 h[2]; uint32_t u; } c;
  c.h[0] = (__bf16)a; c.h[1] = (__bf16)b;
  return c.u;
}

// ---------------------------------------------------------------------------
// fp32 -> bf16 convert pass (BW-bound). z picks {q,k,v,W}.
// ---------------------------------------------------------------------------
__launch_bounds__(256)
__global__ void cvt_kernel(const float* __restrict__ q, const float* __restrict__ k,
                           const float* __restrict__ v, const float* __restrict__ W,
                           u16* __restrict__ dst) {
  const int z = blockIdx.y;
  if (z == 3 && blockIdx.x >= 128) return;
  const float* __restrict__ src = (z == 0) ? q : (z == 1) ? k : (z == 2) ? v : W;
  u16* __restrict__ d = dst + (size_t)z * 2097152;
  size_t i = ((size_t)blockIdx.x * 256 + threadIdx.x) * 8;
  float4 a = *reinterpret_cast<const float4*>(src + i);
  float4 b = *reinterpret_cast<const float4*>(src + i + 4);
  u16x8 r;
  r[0] = bfbits(a.x); r[1] = bfbits(a.y); r[2] = bfbits(a.z); r[3] = bfbits(a.w);
  r[4] = bfbits(b.x); r[5] = bfbits(b.y); r[6] = bfbits(b.z); r[7] = bfbits(b.w);
  *reinterpret_cast<u16x8*>(d + i) = r;
}

// ---------------------------------------------------------------------------
// Projection GEMM (bf16 in): P = relu(X @ W^T + b).
// Q pre-scaled by 0.125*log2(e) so attention uses exp2 directly.
// 128x128 tile, BK=64 -> 32 MFMA per barrier pair, 8 k-steps.
// Grid 384 = 8 xcd * 12 m * 4 n (n innermost for L2 reuse of X panel).
// ---------------------------------------------------------------------------
__launch_bounds__(256)
__global__ void proj_kernel(const u16* __restrict__ Xall, const u16* __restrict__ Wb,
                            const float* __restrict__ bias,
                            u16* __restrict__ Qw, u16* __restrict__ Kw,
                            u16* __restrict__ Vt) {
  __shared__ u16 As[128][72];
  __shared__ u16 Bs[128][72];
  const int bid = blockIdx.x;
  const int xcd = bid & 7;
  const int u = bid >> 3;               // 0..47
  const int n0 = (u & 3) * 128;
  const int mi = u >> 2;                // 0..11
  const int mg = (xcd * 12 + mi) * 128; // global m in [0, 12288)
  const int z = mg >> 12;               // 0..2
  const int m_in = mg & 4095;
  const u16* __restrict__ X = Xall + (size_t)z * 2097152 + (size_t)m_in * DM;

  const int t = threadIdx.x;
  const int lane = t & 63;
  const int wid = t >> 6;
  const int wr = wid >> 1, wc = wid & 1;
  const int fr = lane & 15, fg = lane >> 4;
  const int srow = t >> 1, scol = (t & 1) * 32;

  f32x4 acc[4][4] = {};

  for (int k0 = 0; k0 < DM; k0 += 64) {
    #pragma unroll
    for (int kk = 0; kk < 4; ++kk) {
      *reinterpret_cast<uint4*>(&As[srow][scol + kk*8]) =
          *reinterpret_cast<const uint4*>(X + (size_t)srow * DM + k0 + scol + kk*8);
      *reinterpret_cast<uint4*>(&Bs[srow][scol + kk*8]) =
          *reinterpret_cast<const uint4*>(Wb + (size_t)(n0 + srow) * DM + k0 + scol + kk*8);
    }
    __syncthreads();
    #pragma unroll
    for (int c = 0; c < 2; ++c) {
      bf16x8 af[4], bfr[4];
      #pragma unroll
      for (int mi2 = 0; mi2 < 4; ++mi2)
        af[mi2] = *reinterpret_cast<const bf16x8*>(&As[wr*64 + mi2*16 + fr][c*32 + fg*8]);
      #pragma unroll
      for (int ni = 0; ni < 4; ++ni)
        bfr[ni] = *reinterpret_cast<const bf16x8*>(&Bs[wc*64 + ni*16 + fr][c*32 + fg*8]);
      __builtin_amdgcn_s_setprio(1);
      #pragma unroll
      for (int mi2 = 0; mi2 < 4; ++mi2)
        #pragma unroll
        for (int ni = 0; ni < 4; ++ni)
          acc[mi2][ni] = __builtin_amdgcn_mfma_f32_16x16x32_bf16(af[mi2], bfr[ni], acc[mi2][ni], 0, 0, 0);
      __builtin_amdgcn_s_setprio(0);
    }
    __syncthreads();
  }

  const float QSCALE = 0.125f * 1.44269504089f;
  #pragma unroll
  for (int mi2 = 0; mi2 < 4; ++mi2) {
    #pragma unroll
    for (int ni = 0; ni < 4; ++ni) {
      #pragma unroll
      for (int r = 0; r < 4; ++r) {
        int mloc = m_in + wr*64 + mi2*16 + fg*4 + r;
        int e2 = n0 + wc*64 + ni*16 + fr;
        float vv = acc[mi2][ni][r] + bias[e2];
        if (z == 0) vv *= QSCALE;
        vv = fmaxf(vv, 0.0f);
        u16 bv = bfbits(vv);
        int b = mloc >> 11, sI = mloc & (S_LEN - 1);
        int hh = e2 >> 6, dh = e2 & 63;
        size_t bhh = (size_t)(b * NH + hh);
        if (z == 0)      Qw[(bhh * S_LEN + sI) * DHD + dh] = bv;
        else if (z == 1) Kw[(bhh * S_LEN + sI) * DHD + dh] = bv;
        else             Vt[(bhh * DHD + dh) * S_LEN + sI] = bv;
      }
    }
  }
}

// ---------------------------------------------------------------------------
// Split-K flash attention, 32x32 MFMA, fully in-register (NO LDS).
// S^T = mfma(K, Q): lane owns q=lane&31, 16 k-values. Unnormalized p=exp2(s)
// (post-ReLU scores >= 0, bounded; log2e folded into Q).
// P -> PV B-operand via 8 cvt_pk + 4 v_permlane32_swap (T12 derivation).
// O^T = mfma(V^T, P): 1/l is lane-local at epilogue. Chunks of <=16 steps.
// ---------------------------------------------------------------------------
__launch_bounds__(256)
__global__ void attn_kernel(const u16* __restrict__ Qw, const u16* __restrict__ Kw,
                            const u16* __restrict__ Vt, u16* __restrict__ Opart,
                            float* __restrict__ lbuf, float* __restrict__ out) {
  const int lane = threadIdx.x & 63;
  const int wid = threadIdx.x >> 6;
  const int lam = lane & 31;
  const int h8 = (lane >> 5) << 3;
  const int h4 = h8 >> 1;
  const int bid = blockIdx.x;
  const int bh = bid & 15;               // 2 heads per xcd (bid&7)
  const int u = ((bid >> 4) << 2) + wid; // 0..159, longest-first

  int tile, chunk;
  if (u < 16)      { tile = 16 + u; chunk = 0; }
  else if (u < 48) { int v = u - 16; tile = 32 + (v >> 1); chunk = v & 1; }
  else if (u < 96) { int v = u - 48; tile = 48 + v / 3; chunk = v % 3; }
  else             { int v = u - 96; tile = (15 - (v >> 2)) + ((v & 3) << 4); chunk = tile >> 4; }
  const int nc = (tile >> 4) + 1;
  const int s0 = chunk * 16;
  const int e = (s0 + 16 < tile + 1) ? (s0 + 16) : (tile + 1);
  const int q0 = tile * 32;

  const u16* __restrict__ Qh = Qw + (size_t)bh * S_LEN * DHD;
  const u16* __restrict__ Kh = Kw + (size_t)bh * S_LEN * DHD;
  const u16* __restrict__ Vh = Vt + (size_t)bh * DHD * S_LEN;

  bf16x8 qf[4];
  #pragma unroll
  for (int c = 0; c < 4; ++c)
    qf[c] = *reinterpret_cast<const bf16x8*>(Qh + (size_t)(q0 + lam) * DHD + c*16 + h8);

  bf16x8 kf[4], vf0[2], vf1[2];
  auto loadK = [&](int s) {
    int kb = s * 32;
    #pragma unroll
    for (int c = 0; c < 4; ++c)
      kf[c] = *reinterpret_cast<const bf16x8*>(Kh + (size_t)(kb + lam) * DHD + c*16 + h8);
  };
  auto loadV = [&](int s) {
    int kb = s * 32;
    #pragma unroll
    for (int c2 = 0; c2 < 2; ++c2) {
      vf0[c2] = *reinterpret_cast<const bf16x8*>(Vh + (size_t)lam * S_LEN + kb + c2*16 + h8);
      vf1[c2] = *reinterpret_cast<const bf16x8*>(Vh + (size_t)(32 + lam) * S_LEN + kb + c2*16 + h8);
    }
  };
  loadK(s0);
  loadV(s0);

  f32x16 o0 = {}, o1 = {};
  float lsum = 0.f;

  for (int s = s0; s < e; ++s) {
    f32x16 sc = {};
    __builtin_amdgcn_s_setprio(1);
    #pragma unroll
    for (int c = 0; c < 4; ++c)
      sc = __builtin_amdgcn_mfma_f32_32x32x16_bf16(kf[c], qf[c], sc, 0, 0, 0);
    __builtin_amdgcn_s_setprio(0);
    if (s + 1 < e) loadK(s + 1);          // kf dead after QK issue

    const bool msk = (s == tile);
    float p[16];
    #pragma unroll
    for (int r = 0; r < 16; ++r) {
      float ev = __builtin_amdgcn_exp2f(sc[r]);
      int kc = (r & 3) + ((r >> 2) << 3) + h4;   // row index in 32x32 C-layout
      if (msk && kc > lam) ev = 0.f;             // causal: k_local > q_local
      p[r] = ev;
      lsum += ev;
    }

    // pack P to bf16 pairs; redistribute with permlane32_swap into PV B-frags
    uint32_t X0 = pkbf(p[0], p[1]),  X1 = pkbf(p[2], p[3]);
    uint32_t X2 = pkbf(p[4], p[5]),  X3 = pkbf(p[6], p[7]);
    uint32_t X4 = pkbf(p[8], p[9]),  X5 = pkbf(p[10], p[11]);
    uint32_t X6 = pkbf(p[12], p[13]), X7 = pkbf(p[14], p[15]);
    asm("v_permlane32_swap_b32 %0, %1" : "+v"(X0), "+v"(X2));
    asm("v_permlane32_swap_b32 %0, %1" : "+v"(X1), "+v"(X3));
    asm("v_permlane32_swap_b32 %0, %1" : "+v"(X4), "+v"(X6));
    asm("v_permlane32_swap_b32 %0, %1" : "+v"(X5), "+v"(X7));
    union U8 { uint32_t u[4]; bf16x8 v; };
    U8 pb0, pb1;
    pb0.u[0] = X0; pb0.u[1] = X1; pb0.u[2] = X2; pb0.u[3] = X3;
    pb1.u[0] = X4; pb1.u[1] = X5; pb1.u[2] = X6; pb1.u[3] = X7;

    __builtin_amdgcn_s_setprio(1);
    o0 = __builtin_amdgcn_mfma_f32_32x32x16_bf16(vf0[0], pb0.v, o0, 0, 0, 0);
    o0 = __builtin_amdgcn_mfma_f32_32x32x16_bf16(vf0[1], pb1.v, o0, 0, 0, 0);
    o1 = __builtin_amdgcn_mfma_f32_32x32x16_bf16(vf1[0], pb0.v, o1, 0, 0, 0);
    o1 = __builtin_amdgcn_mfma_f32_32x32x16_bf16(vf1[1], pb1.v, o1, 0, 0, 0);
    __builtin_amdgcn_s_setprio(0);
    if (s + 1 < e) loadV(s + 1);          // vf dead after PV issue
  }

  float l = lsum + __shfl_xor(lsum, 32);  // lane-local row sum (q = lam)

  if (nc == 1) {
    const int b = bh >> 3, hh = bh & 7;
    const float inv = 1.0f / l;
    float* orow = out + (((size_t)(hh * NB + b)) * S_LEN + (q0 + lam)) * DHD;
    #pragma unroll
    for (int r = 0; r < 16; ++r) {
      int d = (r & 3) + ((r >> 2) << 3) + h4;
      orow[d] = o0[r] * inv;
      orow[d + 32] = o1[r] * inv;
    }
  } else {
    const int g = tile >> 4;
    const int off = (g == 1) ? 0 : ((g == 2) ? 32 : 80);
    const int slot = bh * 144 + off + (tile - (g << 4)) * (g + 1) + chunk;
    uint32_t w[16] __attribute__((aligned(16)));
    #pragma unroll
    for (int m = 0; m < 8; ++m) {
      w[m]     = pkbf(o0[2*m], o0[2*m+1]);
      w[8 + m] = pkbf(o1[2*m], o1[2*m+1]);
    }
    u16* op = Opart + (size_t)slot * 2048 + (size_t)lane * 32;
    #pragma unroll
    for (int i = 0; i < 4; ++i)
      *reinterpret_cast<uint4*>(op + i*8) = *reinterpret_cast<const uint4*>(&w[i*4]);
    if (lane < 32) lbuf[slot * 32 + lane] = l;
  }
}

// ---------------------------------------------------------------------------
// Combine split-K partials for tiles 16..63: plain sums (unnormalized softmax).
// ---------------------------------------------------------------------------
__launch_bounds__(64)
__global__ void reduce_kernel(const u16* __restrict__ Opart,
                              const float* __restrict__ lbuf,
                              float* __restrict__ out) {
  const int bid = blockIdx.x;           // 0..767
  const int bh = bid & 15;
  const int tile = 16 + (bid >> 4);
  const int g = tile >> 4;              // 1..3
  const int nc = g + 1;
  const int lane = threadIdx.x & 63;
  const int lam = lane & 31;
  const int h4 = (lane >> 5) << 2;
  const int off = (g == 1) ? 0 : ((g == 2) ? 32 : 80);
  const int slot0 = bh * 144 + off + (tile - (g << 4)) * nc;

  float O[32];
  #pragma unroll
  for (int i = 0; i < 32; ++i) O[i] = 0.f;
  float L = 0.f;

  for (int c = 0; c < nc; ++c) {
    const u16* op = Opart + (size_t)(slot0 + c) * 2048 + (size_t)lane * 32;
    L += lbuf[(slot0 + c) * 32 + lam];
    #pragma unroll
    for (int i = 0; i < 4; ++i) {
      uint4 v = *reinterpret_cast<const uint4*>(op + i*8);
      uint32_t a[4] = {v.x, v.y, v.z, v.w};
      #pragma unroll
      for (int j = 0; j < 4; ++j) {
        O[i*8 + 2*j]     += bits2f((u16)(a[j] & 0xFFFFu));
        O[i*8 + 2*j + 1] += bits2f((u16)(a[j] >> 16));
      }
    }
  }

  const int b = bh >> 3, hh = bh & 7;
  const float inv = 1.0f / L;
  float* orow = out + (((size_t)(hh * NB + b)) * S_LEN + (tile*32 + lam)) * DHD;
  #pragma unroll
  for (int r = 0; r < 16; ++r) {
    int d = (r & 3) + ((r >> 2) << 3) + h4;
    orow[d] = O[r] * inv;
    orow[d + 32] = O[16 + r] * inv;
  }
}

extern "C" void kernel_launch(void* const* d_in, const int* in_sizes, int n_in,
                              void* d_out, int out_size, void* d_ws, size_t ws_size,
                              hipStream_t stream) {
  const float* q = (const float*)d_in[0];
  const float* k = (const float*)d_in[1];
  const float* v = (const float*)d_in[2];
  const float* W = (const float*)d_in[3];
  const float* b = (const float*)d_in[4];

  const size_t elems = (size_t)NB * NH * S_LEN * DHD;  // 2,097,152
  u16* Qw = (u16*)d_ws;
  u16* Kw = Qw + elems;
  u16* Vt = Kw + elems;
  u16* Xb = Vt + elems;                 // 16 MiB (q,k,v,W bf16)
  // Opart overlaps Xb (Xb consumed by proj before attn writes partials):
  // 2304 slots * 4 KB = 9.4 MiB < 16 MiB
  u16* Opart = Xb;
  float* lbuf = (float*)(Xb + 4 * elems);  // 2304*32*4B = 294 KiB

  cvt_kernel<<<dim3(1024, 4), dim3(256), 0, stream>>>(q, k, v, W, Xb);

  proj_kernel<<<dim3(384), dim3(256), 0, stream>>>(Xb, Xb + 3 * elems, b, Qw, Kw, Vt);

  attn_kernel<<<dim3(640), dim3(256), 0, stream>>>(Qw, Kw, Vt, Opart, lbuf, (float*)d_out);

  reduce_kernel<<<dim3(768), dim3(64), 0, stream>>>(Opart, lbuf, (float*)d_out);
}

// Round 7
// 74.941 us; speedup vs baseline: 1.1953x; 1.1953x over previous
//
#include <hip/hip_runtime.h>
#include <hip/hip_bf16.h>
#include <cstdint>
#include <cstddef>

typedef __bf16 bf16_t;
typedef bf16_t bf16x8 __attribute__((ext_vector_type(8)));
typedef float f32x4 __attribute__((ext_vector_type(4)));
typedef float f32x16 __attribute__((ext_vector_type(16)));
typedef unsigned short u16;
typedef u16 u16x8 __attribute__((ext_vector_type(8)));

#define S_LEN 2048
#define NB 2
#define NH 8
#define DHD 64
#define DM 512
#define SLOTS_PER_BH 228   // sum over tiles t>=10 of ceil((t+1)/10)

static __device__ __forceinline__ u16 bfbits(float f) {
  union { __bf16 h; u16 u; } c; c.h = (__bf16)f; return c.u;
}
static __device__ __forceinline__ float bits2f(u16 b) {
  union { u16 u; __bf16 h; } c; c.u = b; return (float)c.h;
}
static __device__ __forceinline__ uint32_t pkbf(float a, float b) {
  union { __bf16 h[2]; uint32_t u; } c;
  c.h[0] = (__bf16)a; c.h[1] = (__bf16)b;
  return c.u;
}

// ---------------------------------------------------------------------------
// Projection GEMM, fused fp32->bf16: P = relu(X @ W^T + b).
// Q pre-scaled by 0.125*log2(e). Tile 128(M)x64(N), BK=32, 4 waves.
// Epilogue re-layouts through LDS so ALL global stores are 64B coalesced.
// Grid 768 = 8 xcd * 12 m * 8 n (n innermost -> same-X-panel blocks share L2).
// ---------------------------------------------------------------------------
__launch_bounds__(256, 2)
__global__ void proj_kernel(const float* __restrict__ Xq, const float* __restrict__ Xk,
                            const float* __restrict__ Xv, const float* __restrict__ W,
                            const float* __restrict__ bias,
                            u16* __restrict__ Qw, u16* __restrict__ Kw,
                            u16* __restrict__ Vt) {
  __shared__ u16 POOL[9216];   // staging: As 128x40 @0, Bs 64x40 @5120; epilogue reuse
  const int bid = blockIdx.x;
  const int xcd = bid & 7;
  const int u = bid >> 3;               // 0..95
  const int n0 = (u & 7) * 64;
  const int mi = u >> 3;                // 0..11
  const int mg = (xcd * 12 + mi) * 128;
  const int z = mg >> 12;               // 0..2
  const int m_in = mg & 4095;
  const int b = m_in >> 11;
  const int s0m = m_in & (S_LEN - 1);
  const int hh = n0 >> 6;
  const float* __restrict__ X = (z == 0) ? Xq : ((z == 1) ? Xk : Xv);
  X += (size_t)m_in * DM;

  const int t = threadIdx.x;
  const int lane = t & 63;
  const int wid = t >> 6;
  const int wr = wid >> 1, wc = wid & 1;
  const int fr = lane & 15, fg = lane >> 4;

  f32x4 acc[4][2] = {};

  const int arow = t >> 1, acb = (t & 1) * 16;
  const int brow = t >> 2, bcb = (t & 3) * 8;

  for (int k0 = 0; k0 < DM; k0 += 32) {
    {
      const float* ap = X + (size_t)arow * DM + k0 + acb;
      float4 a0 = *(const float4*)ap, a1 = *(const float4*)(ap + 4);
      float4 a2 = *(const float4*)(ap + 8), a3 = *(const float4*)(ap + 12);
      u16x8 r0, r1;
      r0[0]=bfbits(a0.x); r0[1]=bfbits(a0.y); r0[2]=bfbits(a0.z); r0[3]=bfbits(a0.w);
      r0[4]=bfbits(a1.x); r0[5]=bfbits(a1.y); r0[6]=bfbits(a1.z); r0[7]=bfbits(a1.w);
      r1[0]=bfbits(a2.x); r1[1]=bfbits(a2.y); r1[2]=bfbits(a2.z); r1[3]=bfbits(a2.w);
      r1[4]=bfbits(a3.x); r1[5]=bfbits(a3.y); r1[6]=bfbits(a3.z); r1[7]=bfbits(a3.w);
      *(u16x8*)&POOL[arow*40 + acb] = r0;
      *(u16x8*)&POOL[arow*40 + acb + 8] = r1;
      const float* bp = W + (size_t)(n0 + brow) * DM + k0 + bcb;
      float4 b0 = *(const float4*)bp, b1 = *(const float4*)(bp + 4);
      u16x8 rb;
      rb[0]=bfbits(b0.x); rb[1]=bfbits(b0.y); rb[2]=bfbits(b0.z); rb[3]=bfbits(b0.w);
      rb[4]=bfbits(b1.x); rb[5]=bfbits(b1.y); rb[6]=bfbits(b1.z); rb[7]=bfbits(b1.w);
      *(u16x8*)&POOL[5120 + brow*40 + bcb] = rb;
    }
    __syncthreads();
    bf16x8 af[4], bfr[2];
    #pragma unroll
    for (int m2 = 0; m2 < 4; ++m2)
      af[m2] = *(const bf16x8*)&POOL[(wr*64 + m2*16 + fr)*40 + fg*8];
    #pragma unroll
    for (int ni = 0; ni < 2; ++ni)
      bfr[ni] = *(const bf16x8*)&POOL[5120 + (wc*32 + ni*16 + fr)*40 + fg*8];
    __builtin_amdgcn_s_setprio(1);
    #pragma unroll
    for (int m2 = 0; m2 < 4; ++m2)
      #pragma unroll
      for (int ni = 0; ni < 2; ++ni)
        acc[m2][ni] = __builtin_amdgcn_mfma_f32_16x16x32_bf16(af[m2], bfr[ni], acc[m2][ni], 0, 0, 0);
    __builtin_amdgcn_s_setprio(0);
    __syncthreads();
  }

  const float QSCALE = 0.125f * 1.44269504089f;
  const size_t bhh = (size_t)(b * NH + hh);

  if (z == 2) {
    // stage C^T[e][m] (stride 136), 8B writes; then coalesced rows -> Vt[bh][dh][s]
    #pragma unroll
    for (int m2 = 0; m2 < 4; ++m2) {
      #pragma unroll
      for (int ni = 0; ni < 2; ++ni) {
        int e = wc*32 + ni*16 + fr;
        int m = wr*64 + m2*16 + fg*4;
        float v0 = fmaxf(acc[m2][ni][0] + bias[n0 + e], 0.f);
        float v1 = fmaxf(acc[m2][ni][1] + bias[n0 + e], 0.f);
        float v2 = fmaxf(acc[m2][ni][2] + bias[n0 + e], 0.f);
        float v3 = fmaxf(acc[m2][ni][3] + bias[n0 + e], 0.f);
        uint2 w; w.x = pkbf(v0, v1); w.y = pkbf(v2, v3);
        *(uint2*)&POOL[e*136 + m] = w;
      }
    }
    __syncthreads();
    const int e = t >> 2, mc = (t & 3) * 32;
    u16* dst = Vt + (bhh * DHD + e) * S_LEN + s0m + mc;
    #pragma unroll
    for (int i = 0; i < 4; ++i)
      *(uint4*)(dst + i*8) = *(const uint4*)&POOL[e*136 + mc + i*8];
  } else {
    // stage C[m][e] (stride 72), b16 writes; then coalesced rows -> Qw/Kw[bh][s][dh]
    #pragma unroll
    for (int m2 = 0; m2 < 4; ++m2) {
      #pragma unroll
      for (int ni = 0; ni < 2; ++ni) {
        int e = wc*32 + ni*16 + fr;
        float bv = bias[n0 + e];
        #pragma unroll
        for (int r = 0; r < 4; ++r) {
          float v = acc[m2][ni][r] + bv;
          if (z == 0) v *= QSCALE;
          v = fmaxf(v, 0.f);
          POOL[(wr*64 + m2*16 + fg*4 + r)*72 + e] = bfbits(v);
        }
      }
    }
    __syncthreads();
    const int mrow = t >> 1, ec = (t & 1) * 32;
    u16* dst = ((z == 0) ? Qw : Kw) + (bhh * S_LEN + s0m + mrow) * DHD + ec;
    #pragma unroll
    for (int i = 0; i < 4; ++i)
      *(uint4*)(dst + i*8) = *(const uint4*)&POOL[mrow*72 + ec + i*8];
  }
}

// ---------------------------------------------------------------------------
// Split-K flash attention, 32x32 MFMA, in-register softpack (permlane T12),
// unnormalized p=exp2(s) (post-ReLU scores >= 0; log2e folded into Q).
// Each iteration processes TWO independent 32-row KV sub-tiles (ILP), with
// K/V for the next iteration prefetched a full iteration ahead.
// Chunks of 10 32-blocks; 3808 waves (4/block, same-bh per block group).
// ---------------------------------------------------------------------------
__launch_bounds__(256, 2)
__global__ void attn_kernel(const u16* __restrict__ Qw, const u16* __restrict__ Kw,
                            const u16* __restrict__ Vt, u16* __restrict__ Opart,
                            float* __restrict__ lbuf, float* __restrict__ out) {
  const int lane = threadIdx.x & 63;
  const int wid = threadIdx.x >> 6;
  const int lam = lane & 31;
  const int h8 = (lane >> 5) << 3;
  const int h4 = h8 >> 1;
  const int bid = blockIdx.x;
  const int bh = bid & 15;               // xcd = bid&7 -> heads (b0,h),(b1,h) per XCD
  const int u = (bid >> 4) * 4 + wid;    // 0..239
  if (u >= 238) return;
  const int j = 237 - u;                 // longest-ish first
  int g = 0;
  #pragma unroll
  for (int i = 1; i < 7; ++i) g += (j >= 5*i*(i+1)) ? 1 : 0;
  const int r0 = j - 5*g*(g+1);
  const int tile = 10*g + r0 / (g+1);
  const int chunk = r0 % (g+1);
  const int s0 = chunk * 10;
  const int cnt0 = tile + 1 - s0;
  const int cnt = (cnt0 < 10) ? cnt0 : 10;
  const int q0 = tile * 32;

  const u16* __restrict__ Qh = Qw + (size_t)bh * S_LEN * DHD;
  const u16* __restrict__ Kh = Kw + (size_t)bh * S_LEN * DHD;
  const u16* __restrict__ Vh = Vt + (size_t)bh * DHD * S_LEN;

  bf16x8 qf[4];
  #pragma unroll
  for (int c = 0; c < 4; ++c)
    qf[c] = *(const bf16x8*)(Qh + (size_t)(q0 + lam) * DHD + c*16 + h8);

  f32x16 o0 = {}, o1 = {};
  float lsum = 0.f;

  bf16x8 kA[4], kB[4], vA0[2], vA1[2], vB0[2], vB1[2];
  auto loadKA = [&](int kb) {
    #pragma unroll
    for (int c = 0; c < 4; ++c)
      kA[c] = *(const bf16x8*)(Kh + (size_t)(kb + lam) * DHD + c*16 + h8);
  };
  auto loadKB = [&](int kb) {
    #pragma unroll
    for (int c = 0; c < 4; ++c)
      kB[c] = *(const bf16x8*)(Kh + (size_t)(kb + 32 + lam) * DHD + c*16 + h8);
  };
  auto loadVA = [&](int kb) {
    #pragma unroll
    for (int c2 = 0; c2 < 2; ++c2) {
      vA0[c2] = *(const bf16x8*)(Vh + (size_t)lam * S_LEN + kb + c2*16 + h8);
      vA1[c2] = *(const bf16x8*)(Vh + (size_t)(32 + lam) * S_LEN + kb + c2*16 + h8);
    }
  };
  auto loadVB = [&](int kb) {
    #pragma unroll
    for (int c2 = 0; c2 < 2; ++c2) {
      vB0[c2] = *(const bf16x8*)(Vh + (size_t)lam * S_LEN + kb + 32 + c2*16 + h8);
      vB1[c2] = *(const bf16x8*)(Vh + (size_t)(32 + lam) * S_LEN + kb + 32 + c2*16 + h8);
    }
  };

  // exp2 + causal mask + pack P into the two PV B-fragments (verified T12 path)
  auto softpack = [&](const f32x16& sc, bool msk, bf16x8& pb0v, bf16x8& pb1v) {
    float p[16];
    #pragma unroll
    for (int r = 0; r < 16; ++r) {
      float ev = __builtin_amdgcn_exp2f(sc[r]);
      int kc = (r & 3) + ((r >> 2) << 3) + h4;
      if (msk && kc > lam) ev = 0.f;
      p[r] = ev;
      lsum += ev;
    }
    uint32_t X0 = pkbf(p[0], p[1]),  X1 = pkbf(p[2], p[3]);
    uint32_t X2 = pkbf(p[4], p[5]),  X3 = pkbf(p[6], p[7]);
    uint32_t X4 = pkbf(p[8], p[9]),  X5 = pkbf(p[10], p[11]);
    uint32_t X6 = pkbf(p[12], p[13]), X7 = pkbf(p[14], p[15]);
    asm("v_permlane32_swap_b32 %0, %1" : "+v"(X0), "+v"(X2));
    asm("v_permlane32_swap_b32 %0, %1" : "+v"(X1), "+v"(X3));
    asm("v_permlane32_swap_b32 %0, %1" : "+v"(X4), "+v"(X6));
    asm("v_permlane32_swap_b32 %0, %1" : "+v"(X5), "+v"(X7));
    union U8 { uint32_t u[4]; bf16x8 v; };
    U8 a, bU;
    a.u[0] = X0; a.u[1] = X1; a.u[2] = X2; a.u[3] = X3;
    bU.u[0] = X4; bU.u[1] = X5; bU.u[2] = X6; bU.u[3] = X7;
    pb0v = a.v; pb1v = bU.v;
  };
  auto pvA = [&](const bf16x8& p0, const bf16x8& p1) {
    o0 = __builtin_amdgcn_mfma_f32_32x32x16_bf16(vA0[0], p0, o0, 0, 0, 0);
    o0 = __builtin_amdgcn_mfma_f32_32x32x16_bf16(vA0[1], p1, o0, 0, 0, 0);
    o1 = __builtin_amdgcn_mfma_f32_32x32x16_bf16(vA1[0], p0, o1, 0, 0, 0);
    o1 = __builtin_amdgcn_mfma_f32_32x32x16_bf16(vA1[1], p1, o1, 0, 0, 0);
  };
  auto pvB = [&](const bf16x8& p0, const bf16x8& p1) {
    o0 = __builtin_amdgcn_mfma_f32_32x32x16_bf16(vB0[0], p0, o0, 0, 0, 0);
    o0 = __builtin_amdgcn_mfma_f32_32x32x16_bf16(vB0[1], p1, o0, 0, 0, 0);
    o1 = __builtin_amdgcn_mfma_f32_32x32x16_bf16(vB1[0], p0, o1, 0, 0, 0);
    o1 = __builtin_amdgcn_mfma_f32_32x32x16_bf16(vB1[1], p1, o1, 0, 0, 0);
  };

  int kb = s0 * 32;
  if (cnt == 1) {
    loadKA(kb); loadVA(kb);
    f32x16 sc = {};
    #pragma unroll
    for (int c = 0; c < 4; ++c)
      sc = __builtin_amdgcn_mfma_f32_32x32x16_bf16(kA[c], qf[c], sc, 0, 0, 0);
    bf16x8 p0, p1;
    softpack(sc, true, p0, p1);
    pvA(p0, p1);
  } else {
    const int npair = cnt >> 1, rem = cnt & 1;
    loadKA(kb); loadKB(kb); loadVA(kb); loadVB(kb);
    for (int ip = 0; ip < npair; ++ip, kb += 64) {
      const bool last = (ip == npair - 1);
      const bool maskB = ((kb >> 5) + 1) == tile;
      f32x16 sA = {}, sB = {};
      __builtin_amdgcn_s_setprio(1);
      #pragma unroll
      for (int c = 0; c < 4; ++c)
        sA = __builtin_amdgcn_mfma_f32_32x32x16_bf16(kA[c], qf[c], sA, 0, 0, 0);
      #pragma unroll
      for (int c = 0; c < 4; ++c)
        sB = __builtin_amdgcn_mfma_f32_32x32x16_bf16(kB[c], qf[c], sB, 0, 0, 0);
      __builtin_amdgcn_s_setprio(0);
      if (!last)      { loadKA(kb + 64); loadKB(kb + 64); }
      else if (rem)   { loadKA(kb + 64); }
      bf16x8 a0, a1, b0, b1;
      softpack(sA, false, a0, a1);
      softpack(sB, maskB, b0, b1);
      __builtin_amdgcn_s_setprio(1);
      pvA(a0, a1);
      pvB(b0, b1);
      __builtin_amdgcn_s_setprio(0);
      if (!last)      { loadVA(kb + 64); loadVB(kb + 64); }
      else if (rem)   { loadVA(kb + 64); }
    }
    if (rem) {                      // final single 32-block == diagonal
      f32x16 sc = {};
      #pragma unroll
      for (int c = 0; c < 4; ++c)
        sc = __builtin_amdgcn_mfma_f32_32x32x16_bf16(kA[c], qf[c], sc, 0, 0, 0);
      bf16x8 p0, p1;
      softpack(sc, true, p0, p1);
      pvA(p0, p1);
    }
  }

  float l = lsum + __shfl_xor(lsum, 32);

  if (g == 0) {
    const int b = bh >> 3, hh = bh & 7;
    const float inv = 1.0f / l;
    float* orow = out + (((size_t)(hh * NB + b)) * S_LEN + (q0 + lam)) * DHD;
    #pragma unroll
    for (int r = 0; r < 16; ++r) {
      int d = (r & 3) + ((r >> 2) << 3) + h4;
      orow[d] = o0[r] * inv;
      orow[d + 32] = o1[r] * inv;
    }
  } else {
    const int slot = bh * SLOTS_PER_BH + 5*g*(g+1) - 10 + (tile - 10*g) * (g + 1) + chunk;
    uint32_t w[16] __attribute__((aligned(16)));
    #pragma unroll
    for (int m = 0; m < 8; ++m) {
      w[m]     = pkbf(o0[2*m], o0[2*m+1]);
      w[8 + m] = pkbf(o1[2*m], o1[2*m+1]);
    }
    u16* op = Opart + (size_t)slot * 2048 + (size_t)lane * 32;
    #pragma unroll
    for (int i = 0; i < 4; ++i)
      *(uint4*)(op + i*8) = *(const uint4*)&w[i*4];
    if (lane < 32) lbuf[slot * 32 + lane] = l;
  }
}

// ---------------------------------------------------------------------------
// Combine split-K partials for tiles 10..63: plain sums (unnormalized softmax).
// ---------------------------------------------------------------------------
__launch_bounds__(64)
__global__ void reduce_kernel(const u16* __restrict__ Opart,
                              const float* __restrict__ lbuf,
                              float* __restrict__ out) {
  const int bid = blockIdx.x;           // 0..863
  const int bh = bid & 15;
  const int tile = 10 + (bid >> 4);     // 10..63
  const int g = tile / 10;              // 1..6
  const int nc = g + 1;
  const int lane = threadIdx.x & 63;
  const int lam = lane & 31;
  const int h4 = (lane >> 5) << 2;
  const int slot0 = bh * SLOTS_PER_BH + 5*g*(g+1) - 10 + (tile - 10*g) * nc;

  float O[32];
  #pragma unroll
  for (int i = 0; i < 32; ++i) O[i] = 0.f;
  float L = 0.f;

  for (int c = 0; c < nc; ++c) {
    const u16* op = Opart + (size_t)(slot0 + c) * 2048 + (size_t)lane * 32;
    L += lbuf[(slot0 + c) * 32 + lam];
    #pragma unroll
    for (int i = 0; i < 4; ++i) {
      uint4 v = *(const uint4*)(op + i*8);
      uint32_t a[4] = {v.x, v.y, v.z, v.w};
      #pragma unroll
      for (int jj = 0; jj < 4; ++jj) {
        O[i*8 + 2*jj]     += bits2f((u16)(a[jj] & 0xFFFFu));
        O[i*8 + 2*jj + 1] += bits2f((u16)(a[jj] >> 16));
      }
    }
  }

  const int b = bh >> 3, hh = bh & 7;
  const float inv = 1.0f / L;
  float* orow = out + (((size_t)(hh * NB + b)) * S_LEN + (tile*32 + lam)) * DHD;
  #pragma unroll
  for (int r = 0; r < 16; ++r) {
    int d = (r & 3) + ((r >> 2) << 3) + h4;
    orow[d] = O[r] * inv;
    orow[d + 32] = O[16 + r] * inv;
  }
}

extern "C" void kernel_launch(void* const* d_in, const int* in_sizes, int n_in,
                              void* d_out, int out_size, void* d_ws, size_t ws_size,
                              hipStream_t stream) {
  const float* q = (const float*)d_in[0];
  const float* k = (const float*)d_in[1];
  const float* v = (const float*)d_in[2];
  const float* W = (const float*)d_in[3];
  const float* b = (const float*)d_in[4];

  const size_t elems = (size_t)NB * NH * S_LEN * DHD;  // 2,097,152 (4 MiB bf16 each)
  u16* Qw = (u16*)d_ws;
  u16* Kw = Qw + elems;
  u16* Vt = Kw + elems;
  u16* Opart = Vt + elems;                             // 3648 slots * 4 KiB = 14.25 MiB
  float* lbuf = (float*)(Opart + (size_t)16 * SLOTS_PER_BH * 2048);  // ~456 KiB

  proj_kernel<<<dim3(768), dim3(256), 0, stream>>>(q, k, v, W, b, Qw, Kw, Vt);

  attn_kernel<<<dim3(960), dim3(256), 0, stream>>>(Qw, Kw, Vt, Opart, lbuf, (float*)d_out);

  reduce_kernel<<<dim3(864), dim3(64), 0, stream>>>(Opart, lbuf, (float*)d_out);
}

// Round 8
// 59.985 us; speedup vs baseline: 1.4933x; 1.2493x over previous
//
#include <hip/hip_runtime.h>
#include <hip/hip_bf16.h>
#include <cstdint>
#include <cstddef>

typedef __bf16 bf16_t;
typedef bf16_t bf16x8 __attribute__((ext_vector_type(8)));
typedef float f32x4 __attribute__((ext_vector_type(4)));
typedef float f32x16 __attribute__((ext_vector_type(16)));
typedef unsigned short u16;
typedef u16 u16x8 __attribute__((ext_vector_type(8)));

#define S_LEN 2048
#define NB 2
#define NH 8
#define DHD 64
#define DM 512

static __device__ __forceinline__ u16 bfbits(float f) {
  union { __bf16 h; u16 u; } c; c.h = (__bf16)f; return c.u;
}
static __device__ __forceinline__ float bits2f(u16 b) {
  union { u16 u; __bf16 h; } c; c.u = b; return (float)c.h;
}
static __device__ __forceinline__ uint32_t pkbf(float a, float b) {
  union { __bf16 h[2]; uint32_t u; } c;
  c.h[0] = (__bf16)a; c.h[1] = (__bf16)b;
  return c.u;
}

// slots for split-K partials: per bh, qb 5..15, 4 waves, nc chunks
static __device__ __forceinline__ int slot_of(int bh, int t32, int chunk) {
  int qb = t32 >> 2;
  int nc = (2 * (qb + 1) + 9) / 10;
  int off;
  if (qb < 10) off = (qb - 5) * 8;
  else if (qb < 15) off = 40 + (qb - 10) * 12;
  else off = 100;
  return bh * 116 + off + (t32 & 3) * nc + chunk;
}

// ---------------------------------------------------------------------------
// Projection GEMM, fused fp32->bf16, reg-staged double-buffered LDS.
// P = relu(X @ W^T + b); Q pre-scaled by 0.125*log2(e).
// Tile 128(M)x64(N), BK=32, 4 waves, 1 barrier per k-step.
// Q,K -> [B,H,S,64]; V -> s-tiled transpose [B,H][s/64][d][s%64].
// ---------------------------------------------------------------------------
__launch_bounds__(256, 3)
__global__ void proj_kernel(const float* __restrict__ Xq, const float* __restrict__ Xk,
                            const float* __restrict__ Xv, const float* __restrict__ W,
                            const float* __restrict__ bias,
                            u16* __restrict__ Qw, u16* __restrict__ Kw,
                            u16* __restrict__ Vt64) {
  __shared__ u16 PL[2][7680];   // A 128x40 @0, B 64x40 @5120
  const int bid = blockIdx.x;
  const int xcd = bid & 7;
  const int u = bid >> 3;               // 0..95
  const int n0 = (u & 7) * 64;
  const int mi = u >> 3;                // 0..11
  const int mg = (xcd * 12 + mi) * 128;
  const int z = mg >> 12;               // 0..2
  const int m_in = mg & 4095;
  const int b = m_in >> 11;
  const int s0m = m_in & (S_LEN - 1);
  const int hh = n0 >> 6;
  const float* __restrict__ X = (z == 0) ? Xq : ((z == 1) ? Xk : Xv);
  X += (size_t)m_in * DM;

  const int t = threadIdx.x;
  const int lane = t & 63;
  const int wid = t >> 6;
  const int wr = wid >> 1, wc = wid & 1;
  const int fr = lane & 15, fg = lane >> 4;
  const int arow = t >> 1, acb = (t & 1) * 16;
  const int brow = t >> 2, bcb = (t & 3) * 8;

  f32x4 acc[4][2] = {};
  float4 ar[4]; float4 brg[2];

  auto pload = [&](int k0) {
    const float* ap = X + (size_t)arow * DM + k0 + acb;
    ar[0] = *(const float4*)ap;       ar[1] = *(const float4*)(ap + 4);
    ar[2] = *(const float4*)(ap + 8); ar[3] = *(const float4*)(ap + 12);
    const float* bp = W + (size_t)(n0 + brow) * DM + k0 + bcb;
    brg[0] = *(const float4*)bp; brg[1] = *(const float4*)(bp + 4);
  };
  auto pwrite = [&](int bf) {
    u16x8 r0, r1, rb;
    r0[0]=bfbits(ar[0].x); r0[1]=bfbits(ar[0].y); r0[2]=bfbits(ar[0].z); r0[3]=bfbits(ar[0].w);
    r0[4]=bfbits(ar[1].x); r0[5]=bfbits(ar[1].y); r0[6]=bfbits(ar[1].z); r0[7]=bfbits(ar[1].w);
    r1[0]=bfbits(ar[2].x); r1[1]=bfbits(ar[2].y); r1[2]=bfbits(ar[2].z); r1[3]=bfbits(ar[2].w);
    r1[4]=bfbits(ar[3].x); r1[5]=bfbits(ar[3].y); r1[6]=bfbits(ar[3].z); r1[7]=bfbits(ar[3].w);
    rb[0]=bfbits(brg[0].x); rb[1]=bfbits(brg[0].y); rb[2]=bfbits(brg[0].z); rb[3]=bfbits(brg[0].w);
    rb[4]=bfbits(brg[1].x); rb[5]=bfbits(brg[1].y); rb[6]=bfbits(brg[1].z); rb[7]=bfbits(brg[1].w);
    *(u16x8*)&PL[bf][arow*40 + acb] = r0;
    *(u16x8*)&PL[bf][arow*40 + acb + 8] = r1;
    *(u16x8*)&PL[bf][5120 + brow*40 + bcb] = rb;
  };

  pload(0);
  pwrite(0);
  int cb = 0;
  for (int i = 0; i < 16; ++i) {
    __syncthreads();
    if (i < 15) pload((i + 1) * 32);
    bf16x8 af[4], bfr[2];
    #pragma unroll
    for (int m2 = 0; m2 < 4; ++m2)
      af[m2] = *(const bf16x8*)&PL[cb][(wr*64 + m2*16 + fr)*40 + fg*8];
    #pragma unroll
    for (int ni = 0; ni < 2; ++ni)
      bfr[ni] = *(const bf16x8*)&PL[cb][5120 + (wc*32 + ni*16 + fr)*40 + fg*8];
    __builtin_amdgcn_s_setprio(1);
    #pragma unroll
    for (int m2 = 0; m2 < 4; ++m2)
      #pragma unroll
      for (int ni = 0; ni < 2; ++ni)
        acc[m2][ni] = __builtin_amdgcn_mfma_f32_16x16x32_bf16(af[m2], bfr[ni], acc[m2][ni], 0, 0, 0);
    __builtin_amdgcn_s_setprio(0);
    if (i < 15) pwrite(cb ^ 1);
    cb ^= 1;
  }
  __syncthreads();

  const float QSCALE = 0.125f * 1.44269504089f;
  const size_t bhh = (size_t)(b * NH + hh);
  u16* pool = &PL[0][0];

  if (z == 2) {
    // stage C^T[e][m] (stride 136); coalesced rows -> Vt64[bh][s/64][d][s%64]
    #pragma unroll
    for (int m2 = 0; m2 < 4; ++m2) {
      #pragma unroll
      for (int ni = 0; ni < 2; ++ni) {
        int e = wc*32 + ni*16 + fr;
        int m = wr*64 + m2*16 + fg*4;
        float bv = bias[n0 + e];
        float v0 = fmaxf(acc[m2][ni][0] + bv, 0.f);
        float v1 = fmaxf(acc[m2][ni][1] + bv, 0.f);
        float v2 = fmaxf(acc[m2][ni][2] + bv, 0.f);
        float v3 = fmaxf(acc[m2][ni][3] + bv, 0.f);
        uint2 w; w.x = pkbf(v0, v1); w.y = pkbf(v2, v3);
        *(uint2*)&pool[e*136 + m] = w;
      }
    }
    __syncthreads();
    const int e = t >> 2, mc = (t & 3) * 32;
    const int sb = (s0m >> 6) + (mc >> 6);
    u16* dst = Vt64 + (((size_t)bhh * 32 + sb) * 64 + e) * 64 + (mc & 63);
    #pragma unroll
    for (int i = 0; i < 4; ++i)
      *(uint4*)(dst + i*8) = *(const uint4*)&pool[e*136 + mc + i*8];
  } else {
    // stage C[m][e] (stride 72); coalesced rows -> Qw/Kw[bh][s][dh]
    #pragma unroll
    for (int m2 = 0; m2 < 4; ++m2) {
      #pragma unroll
      for (int ni = 0; ni < 2; ++ni) {
        int e = wc*32 + ni*16 + fr;
        float bv = bias[n0 + e];
        #pragma unroll
        for (int r = 0; r < 4; ++r) {
          float v = acc[m2][ni][r] + bv;
          if (z == 0) v *= QSCALE;
          v = fmaxf(v, 0.f);
          pool[(wr*64 + m2*16 + fg*4 + r)*72 + e] = bfbits(v);
        }
      }
    }
    __syncthreads();
    const int mrow = t >> 1, ec = (t & 1) * 32;
    u16* dst = ((z == 0) ? Qw : Kw) + (bhh * S_LEN + s0m + mrow) * DHD + ec;
    #pragma unroll
    for (int i = 0; i < 4; ++i)
      *(uint4*)(dst + i*8) = *(const uint4*)&pool[mrow*72 + ec + i*8];
  }
}

// longest-first block table: (qb, chunk) for the 34 blocks per bh
static __device__ const uint8_t QBT[34] = {4,5,6,7,8,9,9,10,10,11,11,12,12,13,13,14,14,14,15,15,15,
                                           3,8,13, 2,7,12, 1,6,11, 0,5,10,15};
static __device__ const uint8_t CKT[34] = {0,0,0,0,0,0,1,0,1,0,1,0,1,0,1,0,1,2,0,1,2,
                                           0,1,2, 0,1,2, 0,1,2, 0,1,2,3};

// ---------------------------------------------------------------------------
// Flash attention: 4 waves/block share double-buffered 64-row K/V LDS tiles
// (coalesced reg-staged loads, XOR-swizzled reads). Each wave owns 32 q-rows.
// Unnormalized p=exp2(s) (post-ReLU scores >= 0; log2e in Q). Split-K chunks
// of <=10 steps; qb<=4 write direct, else partials summed by reduce_kernel.
// ---------------------------------------------------------------------------
__launch_bounds__(256, 3)
__global__ void attn_kernel(const u16* __restrict__ Qw, const u16* __restrict__ Kw,
                            const u16* __restrict__ Vt64, u16* __restrict__ Opart,
                            float* __restrict__ lbuf, float* __restrict__ out) {
  __shared__ u16 KLDS[2][4096];
  __shared__ u16 VLDS[2][4096];
  const int t = threadIdx.x;
  const int lane = t & 63;
  const int wid = t >> 6;
  const int lam = lane & 31;
  const int hi = lane >> 5;
  const int h8 = hi << 3, h4 = hi << 2;
  const int bid = blockIdx.x;
  const int bh = bid & 15;              // xcd = bid&7
  const int u = bid >> 4;               // 0..33
  const int qb = QBT[u], chunk = CKT[u];
  const int steps_total = (qb + 1) * 2;
  const int sc0 = chunk * 10;
  const int sc1e = sc0 + 10;
  const int sc1 = (sc1e < steps_total) ? sc1e : steps_total;
  const int t32 = qb * 4 + wid;
  const int q0 = qb * 128 + wid * 32;

  const u16* __restrict__ Qh = Qw + (size_t)bh * S_LEN * DHD;
  const u16* __restrict__ Kh = Kw + (size_t)bh * S_LEN * DHD;
  const u16* __restrict__ V64 = Vt64 + (size_t)bh * 32 * 64 * 64;

  bf16x8 qf[4];
  #pragma unroll
  for (int c = 0; c < 4; ++c)
    qf[c] = *(const bf16x8*)(Qh + (size_t)(q0 + lam) * DHD + c*16 + h8);

  // staging: thread t covers (row = t>>2, two 16B slots e = 2(t&3), +1)
  const int srow = t >> 2, se = (t & 3) * 2;
  uint4 kr0, kr1, vr0, vr1;
  auto issue = [&](int s) {
    const u16* kp = Kh + (size_t)(s * 64 + srow) * 64 + se * 8;
    kr0 = *(const uint4*)kp; kr1 = *(const uint4*)(kp + 8);
    const u16* vp = V64 + ((size_t)s * 64 + srow) * 64 + se * 8;
    vr0 = *(const uint4*)vp; vr1 = *(const uint4*)(vp + 8);
  };
  const int we0 = (se ^ (srow & 7)) * 8, we1 = ((se + 1) ^ (srow & 7)) * 8;
  auto wr = [&](int bf) {
    *(uint4*)&KLDS[bf][srow*64 + we0] = kr0;
    *(uint4*)&KLDS[bf][srow*64 + we1] = kr1;
    *(uint4*)&VLDS[bf][srow*64 + we0] = vr0;
    *(uint4*)&VLDS[bf][srow*64 + we1] = vr1;
  };

  f32x16 o0 = {}, o1 = {};
  float lsum = 0.f;

  auto softpack = [&](const f32x16& sc, bool msk, bf16x8& pb0v, bf16x8& pb1v) {
    float p[16];
    #pragma unroll
    for (int r = 0; r < 16; ++r) {
      float ev = __builtin_amdgcn_exp2f(sc[r]);
      int kc = (r & 3) + ((r >> 2) << 3) + h4;
      if (msk && kc > lam) ev = 0.f;
      p[r] = ev;
      lsum += ev;
    }
    uint32_t X0 = pkbf(p[0], p[1]),  X1 = pkbf(p[2], p[3]);
    uint32_t X2 = pkbf(p[4], p[5]),  X3 = pkbf(p[6], p[7]);
    uint32_t X4 = pkbf(p[8], p[9]),  X5 = pkbf(p[10], p[11]);
    uint32_t X6 = pkbf(p[12], p[13]), X7 = pkbf(p[14], p[15]);
    asm("v_permlane32_swap_b32 %0, %1" : "+v"(X0), "+v"(X2));
    asm("v_permlane32_swap_b32 %0, %1" : "+v"(X1), "+v"(X3));
    asm("v_permlane32_swap_b32 %0, %1" : "+v"(X4), "+v"(X6));
    asm("v_permlane32_swap_b32 %0, %1" : "+v"(X5), "+v"(X7));
    union U8 { uint32_t u[4]; bf16x8 v; };
    U8 a, bU;
    a.u[0] = X0; a.u[1] = X1; a.u[2] = X2; a.u[3] = X3;
    bU.u[0] = X4; bU.u[1] = X5; bU.u[2] = X6; bU.u[3] = X7;
    pb0v = a.v; pb1v = bU.v;
  };

  issue(sc0);
  wr(0);
  int cb = 0;
  for (int s = sc0; s < sc1; ++s) {
    __syncthreads();
    if (s + 1 < sc1) issue(s + 1);
    const int d2 = t32 - 2 * s;         // A computes if >=0 (diag ==0); B if >=1 (diag ==1)
    bf16x8 a0, a1, b0v, b1v;
    f32x16 sA = {}, sB = {};
    if (d2 >= 0) {
      bf16x8 kA[4];
      #pragma unroll
      for (int c = 0; c < 4; ++c) {
        int r = lam, e = ((2*c + hi) ^ (r & 7)) * 8;
        kA[c] = *(const bf16x8*)&KLDS[cb][r*64 + e];
      }
      __builtin_amdgcn_s_setprio(1);
      #pragma unroll
      for (int c = 0; c < 4; ++c)
        sA = __builtin_amdgcn_mfma_f32_32x32x16_bf16(kA[c], qf[c], sA, 0, 0, 0);
      __builtin_amdgcn_s_setprio(0);
    }
    if (d2 >= 1) {
      bf16x8 kB[4];
      #pragma unroll
      for (int c = 0; c < 4; ++c) {
        int r = 32 + lam, e = ((2*c + hi) ^ (r & 7)) * 8;
        kB[c] = *(const bf16x8*)&KLDS[cb][r*64 + e];
      }
      __builtin_amdgcn_s_setprio(1);
      #pragma unroll
      for (int c = 0; c < 4; ++c)
        sB = __builtin_amdgcn_mfma_f32_32x32x16_bf16(kB[c], qf[c], sB, 0, 0, 0);
      __builtin_amdgcn_s_setprio(0);
    }
    if (d2 >= 0) softpack(sA, d2 == 0, a0, a1);
    if (d2 >= 1) softpack(sB, d2 == 1, b0v, b1v);
    if (d2 >= 0) {
      bf16x8 v0[2], v1[2];
      #pragma unroll
      for (int c2 = 0; c2 < 2; ++c2) {
        int r0 = lam,      e0 = ((2*c2 + hi) ^ (r0 & 7)) * 8;
        int r1 = 32 + lam, e1 = ((2*c2 + hi) ^ (r1 & 7)) * 8;
        v0[c2] = *(const bf16x8*)&VLDS[cb][r0*64 + e0];
        v1[c2] = *(const bf16x8*)&VLDS[cb][r1*64 + e1];
      }
      __builtin_amdgcn_s_setprio(1);
      o0 = __builtin_amdgcn_mfma_f32_32x32x16_bf16(v0[0], a0, o0, 0, 0, 0);
      o0 = __builtin_amdgcn_mfma_f32_32x32x16_bf16(v0[1], a1, o0, 0, 0, 0);
      o1 = __builtin_amdgcn_mfma_f32_32x32x16_bf16(v1[0], a0, o1, 0, 0, 0);
      o1 = __builtin_amdgcn_mfma_f32_32x32x16_bf16(v1[1], a1, o1, 0, 0, 0);
      __builtin_amdgcn_s_setprio(0);
    }
    if (d2 >= 1) {
      bf16x8 v0[2], v1[2];
      #pragma unroll
      for (int c2 = 0; c2 < 2; ++c2) {
        int r0 = lam,      e0 = ((4 + 2*c2 + hi) ^ (r0 & 7)) * 8;
        int r1 = 32 + lam, e1 = ((4 + 2*c2 + hi) ^ (r1 & 7)) * 8;
        v0[c2] = *(const bf16x8*)&VLDS[cb][r0*64 + e0];
        v1[c2] = *(const bf16x8*)&VLDS[cb][r1*64 + e1];
      }
      __builtin_amdgcn_s_setprio(1);
      o0 = __builtin_amdgcn_mfma_f32_32x32x16_bf16(v0[0], b0v, o0, 0, 0, 0);
      o0 = __builtin_amdgcn_mfma_f32_32x32x16_bf16(v0[1], b1v, o0, 0, 0, 0);
      o1 = __builtin_amdgcn_mfma_f32_32x32x16_bf16(v1[0], b0v, o1, 0, 0, 0);
      o1 = __builtin_amdgcn_mfma_f32_32x32x16_bf16(v1[1], b1v, o1, 0, 0, 0);
      __builtin_amdgcn_s_setprio(0);
    }
    if (s + 1 < sc1) wr(cb ^ 1);
    cb ^= 1;
  }

  float l = lsum + __shfl_xor(lsum, 32);

  if (qb <= 4) {
    const int b = bh >> 3, hh = bh & 7;
    const float inv = 1.0f / l;
    float* orow = out + (((size_t)(hh * NB + b)) * S_LEN + (q0 + lam)) * DHD;
    #pragma unroll
    for (int r = 0; r < 16; ++r) {
      int d = (r & 3) + ((r >> 2) << 3) + h4;
      orow[d] = o0[r] * inv;
      orow[d + 32] = o1[r] * inv;
    }
  } else {
    const int slot = slot_of(bh, t32, chunk);
    uint32_t w[16] __attribute__((aligned(16)));
    #pragma unroll
    for (int m = 0; m < 8; ++m) {
      w[m]     = pkbf(o0[2*m], o0[2*m+1]);
      w[8 + m] = pkbf(o1[2*m], o1[2*m+1]);
    }
    u16* op = Opart + (size_t)slot * 2048 + (size_t)lane * 32;
    #pragma unroll
    for (int i = 0; i < 4; ++i)
      *(uint4*)(op + i*8) = *(const uint4*)&w[i*4];
    if (lane < 32) lbuf[slot * 32 + lane] = l;
  }
}

// ---------------------------------------------------------------------------
// Combine split-K partials for tiles with qb>=5 (t32 20..63): plain sums.
// ---------------------------------------------------------------------------
__launch_bounds__(256)
__global__ void reduce_kernel(const u16* __restrict__ Opart,
                              const float* __restrict__ lbuf,
                              float* __restrict__ out) {
  const int t = threadIdx.x;
  const int unit = blockIdx.x * 4 + (t >> 6);   // 0..703
  const int bh = unit & 15;
  const int ti = 20 + (unit >> 4);              // t32 20..63
  const int qb = ti >> 2;
  const int nc = (2 * (qb + 1) + 9) / 10;       // 2..4
  const int lane = t & 63;
  const int lam = lane & 31;
  const int h4 = (lane >> 5) << 2;
  const int slot0 = slot_of(bh, ti, 0);

  float O[32];
  #pragma unroll
  for (int i = 0; i < 32; ++i) O[i] = 0.f;
  float L = 0.f;

  for (int c = 0; c < nc; ++c) {
    const u16* op = Opart + (size_t)(slot0 + c) * 2048 + (size_t)lane * 32;
    L += lbuf[(slot0 + c) * 32 + lam];
    #pragma unroll
    for (int i = 0; i < 4; ++i) {
      uint4 v = *(const uint4*)(op + i*8);
      uint32_t a[4] = {v.x, v.y, v.z, v.w};
      #pragma unroll
      for (int jj = 0; jj < 4; ++jj) {
        O[i*8 + 2*jj]     += bits2f((u16)(a[jj] & 0xFFFFu));
        O[i*8 + 2*jj + 1] += bits2f((u16)(a[jj] >> 16));
      }
    }
  }

  const int b = bh >> 3, hh = bh & 7;
  const float inv = 1.0f / L;
  float* orow = out + (((size_t)(hh * NB + b)) * S_LEN + (ti*32 + lam)) * DHD;
  #pragma unroll
  for (int r = 0; r < 16; ++r) {
    int d = (r & 3) + ((r >> 2) << 3) + h4;
    orow[d] = O[r] * inv;
    orow[d + 32] = O[16 + r] * inv;
  }
}

extern "C" void kernel_launch(void* const* d_in, const int* in_sizes, int n_in,
                              void* d_out, int out_size, void* d_ws, size_t ws_size,
                              hipStream_t stream) {
  const float* q = (const float*)d_in[0];
  const float* k = (const float*)d_in[1];
  const float* v = (const float*)d_in[2];
  const float* W = (const float*)d_in[3];
  const float* b = (const float*)d_in[4];

  const size_t elems = (size_t)NB * NH * S_LEN * DHD;  // 2,097,152
  u16* Qw = (u16*)d_ws;
  u16* Kw = Qw + elems;
  u16* Vt64 = Kw + elems;
  u16* Opart = Vt64 + elems;                           // 1856 slots * 4 KiB = 7.25 MiB
  float* lbuf = (float*)(Opart + (size_t)1856 * 2048); // 232 KiB

  proj_kernel<<<dim3(768), dim3(256), 0, stream>>>(q, k, v, W, b, Qw, Kw, Vt64);

  attn_kernel<<<dim3(544), dim3(256), 0, stream>>>(Qw, Kw, Vt64, Opart, lbuf, (float*)d_out);

  reduce_kernel<<<dim3(176), dim3(256), 0, stream>>>(Opart, lbuf, (float*)d_out);
}

// Round 9
// 51.211 us; speedup vs baseline: 1.7492x; 1.1713x over previous
//
#include <hip/hip_runtime.h>
#include <hip/hip_bf16.h>
#include <cstdint>
#include <cstddef>

typedef __bf16 bf16_t;
typedef bf16_t bf16x8 __attribute__((ext_vector_type(8)));
typedef float f32x4 __attribute__((ext_vector_type(4)));
typedef float f32x16 __attribute__((ext_vector_type(16)));
typedef unsigned short u16;
typedef u16 u16x8 __attribute__((ext_vector_type(8)));

#define S_LEN 2048
#define NB 2
#define NH 8
#define DHD 64
#define DM 512

static __device__ __forceinline__ u16 bfbits(float f) {
  union { __bf16 h; u16 u; } c; c.h = (__bf16)f; return c.u;
}
static __device__ __forceinline__ float bits2f(u16 b) {
  union { u16 u; __bf16 h; } c; c.u = b; return (float)c.h;
}
static __device__ __forceinline__ uint32_t pkbf(float a, float b) {
  union { __bf16 h[2]; uint32_t u; } c;
  c.h[0] = (__bf16)a; c.h[1] = (__bf16)b;
  return c.u;
}
// async global->LDS, 16B per lane; LDS dest is wave-uniform base + lane*16
static __device__ __forceinline__ void gload16(const void* g, void* l) {
  __builtin_amdgcn_global_load_lds(
      (const __attribute__((address_space(1))) uint32_t*)g,
      (__attribute__((address_space(3))) uint32_t*)l, 16, 0, 0);
}

// slots for split-K partials: per bh, qb 5..15, 4 waves, nc chunks
static __device__ __forceinline__ int slot_of(int bh, int t32, int chunk) {
  int qb = t32 >> 2;
  int nc = (2 * (qb + 1) + 9) / 10;
  int off;
  if (qb < 10) off = (qb - 5) * 8;
  else if (qb < 15) off = 40 + (qb - 10) * 12;
  else off = 100;
  return bh * 116 + off + (t32 & 3) * nc + chunk;
}

// ---------------------------------------------------------------------------
// Projection GEMM: P = relu(X @ W^T + b); Q pre-scaled by 0.125*log2(e).
// fp32 staged to LDS via global_load_lds (XOR-pre-swizzled source, linear
// LDS, XOR read) -> zero staging VGPR/VALU; fp32->bf16 cvt at fragment build.
// Tile 128(M)x64(N), BK=32, 16 steps, 1 barrier/step, 2-phase prefetch.
// ---------------------------------------------------------------------------
__launch_bounds__(256, 3)
__global__ void proj_kernel(const float* __restrict__ Xq, const float* __restrict__ Xk,
                            const float* __restrict__ Xv, const float* __restrict__ W,
                            const float* __restrict__ bias,
                            u16* __restrict__ Qw, u16* __restrict__ Kw,
                            u16* __restrict__ Vt64) {
  __shared__ __align__(16) char pool[49152];
  float* AB[2]; float* BB[2];
  AB[0] = (float*)pool;          // 128x32 f32 = 16KB
  AB[1] = AB[0] + 4096;
  BB[0] = AB[1] + 4096;          // 64x32 f32 = 8KB
  BB[1] = BB[0] + 2048;

  const int bid = blockIdx.x;
  const int xcd = bid & 7;
  const int u = bid >> 3;               // 0..95
  const int n0 = (u & 7) * 64;
  const int mi = u >> 3;                // 0..11
  const int mg = (xcd * 12 + mi) * 128;
  const int z = mg >> 12;               // 0..2
  const int m_in = mg & 4095;
  const int b = m_in >> 11;
  const int s0m = m_in & (S_LEN - 1);
  const int hh = n0 >> 6;
  const float* __restrict__ X = (z == 0) ? Xq : ((z == 1) ? Xk : Xv);
  X += (size_t)m_in * DM;

  const int t = threadIdx.x;
  const int lane = t & 63;
  const int wid = t >> 6;
  const int wr = wid >> 1, wc = wid & 1;
  const int fr = lane & 15, fg = lane >> 4;

  f32x4 acc[4][2] = {};

  const int lrow = lane >> 3;           // 0..7 within chunk
  const int lblk = lane & 7;            // 16B block within row

  auto stage = [&](int bf, int k0) {
    #pragma unroll
    for (int i = 0; i < 4; ++i) {       // A: 16 chunks of 1KB, 4 per wave
      int c = wid * 4 + i;
      int r = c * 8 + lrow;
      gload16(X + (size_t)r * DM + k0 + ((lblk ^ (r & 7)) << 2), AB[bf] + c * 256);
    }
    #pragma unroll
    for (int i = 0; i < 2; ++i) {       // B: 8 chunks, 2 per wave
      int c = wid * 2 + i;
      int r = c * 8 + lrow;
      gload16(W + (size_t)(n0 + r) * DM + k0 + ((lblk ^ (r & 7)) << 2), BB[bf] + c * 256);
    }
  };

  stage(0, 0);
  int cb = 0;
  for (int t16 = 0; t16 < 16; ++t16) {
    __syncthreads();                    // drains prior stage (compiler vmcnt)
    if (t16 < 15) stage(cb ^ 1, (t16 + 1) * 32);
    const float* Ac = AB[cb];
    const float* Bc = BB[cb];
    bf16x8 af[4], bfr[2];
    #pragma unroll
    for (int m2 = 0; m2 < 4; ++m2) {
      int r = wr*64 + m2*16 + fr;
      f32x4 lo = *(const f32x4*)&Ac[r*32 + (((2*fg)     ^ (r & 7)) << 2)];
      f32x4 hi = *(const f32x4*)&Ac[r*32 + (((2*fg + 1) ^ (r & 7)) << 2)];
      union { u16x8 s; bf16x8 v; } f;
      f.s[0]=bfbits(lo[0]); f.s[1]=bfbits(lo[1]); f.s[2]=bfbits(lo[2]); f.s[3]=bfbits(lo[3]);
      f.s[4]=bfbits(hi[0]); f.s[5]=bfbits(hi[1]); f.s[6]=bfbits(hi[2]); f.s[7]=bfbits(hi[3]);
      af[m2] = f.v;
    }
    #pragma unroll
    for (int ni = 0; ni < 2; ++ni) {
      int r = wc*32 + ni*16 + fr;
      f32x4 lo = *(const f32x4*)&Bc[r*32 + (((2*fg)     ^ (r & 7)) << 2)];
      f32x4 hi = *(const f32x4*)&Bc[r*32 + (((2*fg + 1) ^ (r & 7)) << 2)];
      union { u16x8 s; bf16x8 v; } f;
      f.s[0]=bfbits(lo[0]); f.s[1]=bfbits(lo[1]); f.s[2]=bfbits(lo[2]); f.s[3]=bfbits(lo[3]);
      f.s[4]=bfbits(hi[0]); f.s[5]=bfbits(hi[1]); f.s[6]=bfbits(hi[2]); f.s[7]=bfbits(hi[3]);
      bfr[ni] = f.v;
    }
    __builtin_amdgcn_s_setprio(1);
    #pragma unroll
    for (int m2 = 0; m2 < 4; ++m2)
      #pragma unroll
      for (int ni = 0; ni < 2; ++ni)
        acc[m2][ni] = __builtin_amdgcn_mfma_f32_16x16x32_bf16(af[m2], bfr[ni], acc[m2][ni], 0, 0, 0);
    __builtin_amdgcn_s_setprio(0);
    cb ^= 1;
  }
  __syncthreads();

  const float QSCALE = 0.125f * 1.44269504089f;
  const size_t bhh = (size_t)(b * NH + hh);
  u16* epi = (u16*)pool;

  if (z == 2) {
    // stage C^T[e][m] (stride 136); coalesced rows -> Vt64[bh][s/64][d][s%64]
    #pragma unroll
    for (int m2 = 0; m2 < 4; ++m2) {
      #pragma unroll
      for (int ni = 0; ni < 2; ++ni) {
        int e = wc*32 + ni*16 + fr;
        int m = wr*64 + m2*16 + fg*4;
        float bv = bias[n0 + e];
        float v0 = fmaxf(acc[m2][ni][0] + bv, 0.f);
        float v1 = fmaxf(acc[m2][ni][1] + bv, 0.f);
        float v2 = fmaxf(acc[m2][ni][2] + bv, 0.f);
        float v3 = fmaxf(acc[m2][ni][3] + bv, 0.f);
        uint2 w; w.x = pkbf(v0, v1); w.y = pkbf(v2, v3);
        *(uint2*)&epi[e*136 + m] = w;
      }
    }
    __syncthreads();
    const int e = t >> 2, mc = (t & 3) * 32;
    const int sb = (s0m >> 6) + (mc >> 6);
    u16* dst = Vt64 + (((size_t)bhh * 32 + sb) * 64 + e) * 64 + (mc & 63);
    #pragma unroll
    for (int i = 0; i < 4; ++i)
      *(uint4*)(dst + i*8) = *(const uint4*)&epi[e*136 + mc + i*8];
  } else {
    // stage C[m][e] (stride 72); coalesced rows -> Qw/Kw[bh][s][dh]
    #pragma unroll
    for (int m2 = 0; m2 < 4; ++m2) {
      #pragma unroll
      for (int ni = 0; ni < 2; ++ni) {
        int e = wc*32 + ni*16 + fr;
        float bv = bias[n0 + e];
        #pragma unroll
        for (int r = 0; r < 4; ++r) {
          float v = acc[m2][ni][r] + bv;
          if (z == 0) v *= QSCALE;
          v = fmaxf(v, 0.f);
          epi[(wr*64 + m2*16 + fg*4 + r)*72 + e] = bfbits(v);
        }
      }
    }
    __syncthreads();
    const int mrow = t >> 1, ec = (t & 1) * 32;
    u16* dst = ((z == 0) ? Qw : Kw) + (bhh * S_LEN + s0m + mrow) * DHD + ec;
    #pragma unroll
    for (int i = 0; i < 4; ++i)
      *(uint4*)(dst + i*8) = *(const uint4*)&epi[mrow*72 + ec + i*8];
  }
}

// longest-first block table: (qb, chunk) for the 34 blocks per bh
static __device__ const uint8_t QBT[34] = {4,5,6,7,8,9,9,10,10,11,11,12,12,13,13,14,14,14,15,15,15,
                                           3,8,13, 2,7,12, 1,6,11, 0,5,10,15};
static __device__ const uint8_t CKT[34] = {0,0,0,0,0,0,1,0,1,0,1,0,1,0,1,0,1,2,0,1,2,
                                           0,1,2, 0,1,2, 0,1,2, 0,1,2,3};

// ---------------------------------------------------------------------------
// Flash attention: 4 waves/block share double-buffered 64-row K/V LDS tiles
// staged via global_load_lds (XOR-pre-swizzled source, same content layout as
// R8). Each wave owns 32 q-rows; unnormalized p=exp2(s); split-K chunks <=10.
// ---------------------------------------------------------------------------
__launch_bounds__(256, 3)
__global__ void attn_kernel(const u16* __restrict__ Qw, const u16* __restrict__ Kw,
                            const u16* __restrict__ Vt64, u16* __restrict__ Opart,
                            float* __restrict__ lbuf, float* __restrict__ out) {
  __shared__ u16 KLDS[2][4096];
  __shared__ u16 VLDS[2][4096];
  const int t = threadIdx.x;
  const int lane = t & 63;
  const int wid = t >> 6;
  const int lam = lane & 31;
  const int hi = lane >> 5;
  const int h8 = hi << 3, h4 = hi << 2;
  const int bid = blockIdx.x;
  const int bh = bid & 15;              // xcd = bid&7
  const int u = bid >> 4;               // 0..33
  const int qb = QBT[u], chunk = CKT[u];
  const int steps_total = (qb + 1) * 2;
  const int sc0 = chunk * 10;
  const int sc1e = sc0 + 10;
  const int sc1 = (sc1e < steps_total) ? sc1e : steps_total;
  const int t32 = qb * 4 + wid;
  const int q0 = qb * 128 + wid * 32;

  const u16* __restrict__ Qh = Qw + (size_t)bh * S_LEN * DHD;
  const u16* __restrict__ Kh = Kw + (size_t)bh * S_LEN * DHD;
  const u16* __restrict__ V64 = Vt64 + (size_t)bh * 32 * 64 * 64;

  bf16x8 qf[4];
  #pragma unroll
  for (int c = 0; c < 4; ++c)
    qf[c] = *(const bf16x8*)(Qh + (size_t)(q0 + lam) * DHD + c*16 + h8);

  const int lrow = lane >> 3;           // 0..7 within chunk
  const int lblk = lane & 7;
  auto stage = [&](int bf, int s) {
    #pragma unroll
    for (int i = 0; i < 2; ++i) {       // K,V: 8 chunks of 1KB each, 2 per wave
      int c = wid * 2 + i;
      int r = c * 8 + lrow;             // 0..63
      int sw = (lblk ^ (r & 7)) << 3;   // XOR-pre-swizzled source block (u16)
      gload16(Kh + (size_t)(s * 64 + r) * 64 + sw, &KLDS[bf][c * 512]);
      gload16(V64 + ((size_t)s * 64 + r) * 64 + sw, &VLDS[bf][c * 512]);
    }
  };

  f32x16 o0 = {}, o1 = {};
  float lsum = 0.f;

  auto softpack = [&](const f32x16& sc, bool msk, bf16x8& pb0v, bf16x8& pb1v) {
    float p[16];
    #pragma unroll
    for (int r = 0; r < 16; ++r) {
      float ev = __builtin_amdgcn_exp2f(sc[r]);
      int kc = (r & 3) + ((r >> 2) << 3) + h4;
      if (msk && kc > lam) ev = 0.f;
      p[r] = ev;
      lsum += ev;
    }
    uint32_t X0 = pkbf(p[0], p[1]),  X1 = pkbf(p[2], p[3]);
    uint32_t X2 = pkbf(p[4], p[5]),  X3 = pkbf(p[6], p[7]);
    uint32_t X4 = pkbf(p[8], p[9]),  X5 = pkbf(p[10], p[11]);
    uint32_t X6 = pkbf(p[12], p[13]), X7 = pkbf(p[14], p[15]);
    asm("v_permlane32_swap_b32 %0, %1" : "+v"(X0), "+v"(X2));
    asm("v_permlane32_swap_b32 %0, %1" : "+v"(X1), "+v"(X3));
    asm("v_permlane32_swap_b32 %0, %1" : "+v"(X4), "+v"(X6));
    asm("v_permlane32_swap_b32 %0, %1" : "+v"(X5), "+v"(X7));
    union U8 { uint32_t u[4]; bf16x8 v; };
    U8 a, bU;
    a.u[0] = X0; a.u[1] = X1; a.u[2] = X2; a.u[3] = X3;
    bU.u[0] = X4; bU.u[1] = X5; bU.u[2] = X6; bU.u[3] = X7;
    pb0v = a.v; pb1v = bU.v;
  };

  stage(0, sc0);
  int cb = 0;
  for (int s = sc0; s < sc1; ++s) {
    __syncthreads();                    // drains prior stage (compiler vmcnt)
    if (s + 1 < sc1) stage(cb ^ 1, s + 1);
    const int d2 = t32 - 2 * s;         // A computes if >=0 (diag ==0); B if >=1 (diag ==1)
    bf16x8 a0, a1, b0v, b1v;
    f32x16 sA = {}, sB = {};
    if (d2 >= 0) {
      bf16x8 kA[4];
      #pragma unroll
      for (int c = 0; c < 4; ++c) {
        int r = lam, e = ((2*c + hi) ^ (r & 7)) * 8;
        kA[c] = *(const bf16x8*)&KLDS[cb][r*64 + e];
      }
      __builtin_amdgcn_s_setprio(1);
      #pragma unroll
      for (int c = 0; c < 4; ++c)
        sA = __builtin_amdgcn_mfma_f32_32x32x16_bf16(kA[c], qf[c], sA, 0, 0, 0);
      __builtin_amdgcn_s_setprio(0);
    }
    if (d2 >= 1) {
      bf16x8 kB[4];
      #pragma unroll
      for (int c = 0; c < 4; ++c) {
        int r = 32 + lam, e = ((2*c + hi) ^ (r & 7)) * 8;
        kB[c] = *(const bf16x8*)&KLDS[cb][r*64 + e];
      }
      __builtin_amdgcn_s_setprio(1);
      #pragma unroll
      for (int c = 0; c < 4; ++c)
        sB = __builtin_amdgcn_mfma_f32_32x32x16_bf16(kB[c], qf[c], sB, 0, 0, 0);
      __builtin_amdgcn_s_setprio(0);
    }
    if (d2 >= 0) softpack(sA, d2 == 0, a0, a1);
    if (d2 >= 1) softpack(sB, d2 == 1, b0v, b1v);
    if (d2 >= 0) {
      bf16x8 v0[2], v1[2];
      #pragma unroll
      for (int c2 = 0; c2 < 2; ++c2) {
        int r0 = lam,      e0 = ((2*c2 + hi) ^ (r0 & 7)) * 8;
        int r1 = 32 + lam, e1 = ((2*c2 + hi) ^ (r1 & 7)) * 8;
        v0[c2] = *(const bf16x8*)&VLDS[cb][r0*64 + e0];
        v1[c2] = *(const bf16x8*)&VLDS[cb][r1*64 + e1];
      }
      __builtin_amdgcn_s_setprio(1);
      o0 = __builtin_amdgcn_mfma_f32_32x32x16_bf16(v0[0], a0, o0, 0, 0, 0);
      o0 = __builtin_amdgcn_mfma_f32_32x32x16_bf16(v0[1], a1, o0, 0, 0, 0);
      o1 = __builtin_amdgcn_mfma_f32_32x32x16_bf16(v1[0], a0, o1, 0, 0, 0);
      o1 = __builtin_amdgcn_mfma_f32_32x32x16_bf16(v1[1], a1, o1, 0, 0, 0);
      __builtin_amdgcn_s_setprio(0);
    }
    if (d2 >= 1) {
      bf16x8 v0[2], v1[2];
      #pragma unroll
      for (int c2 = 0; c2 < 2; ++c2) {
        int r0 = lam,      e0 = ((4 + 2*c2 + hi) ^ (r0 & 7)) * 8;
        int r1 = 32 + lam, e1 = ((4 + 2*c2 + hi) ^ (r1 & 7)) * 8;
        v0[c2] = *(const bf16x8*)&VLDS[cb][r0*64 + e0];
        v1[c2] = *(const bf16x8*)&VLDS[cb][r1*64 + e1];
      }
      __builtin_amdgcn_s_setprio(1);
      o0 = __builtin_amdgcn_mfma_f32_32x32x16_bf16(v0[0], b0v, o0, 0, 0, 0);
      o0 = __builtin_amdgcn_mfma_f32_32x32x16_bf16(v0[1], b1v, o0, 0, 0, 0);
      o1 = __builtin_amdgcn_mfma_f32_32x32x16_bf16(v1[0], b0v, o1, 0, 0, 0);
      o1 = __builtin_amdgcn_mfma_f32_32x32x16_bf16(v1[1], b1v, o1, 0, 0, 0);
      __builtin_amdgcn_s_setprio(0);
    }
    cb ^= 1;
  }

  float l = lsum + __shfl_xor(lsum, 32);

  if (qb <= 4) {
    const int b = bh >> 3, hh = bh & 7;
    const float inv = 1.0f / l;
    float* orow = out + (((size_t)(hh * NB + b)) * S_LEN + (q0 + lam)) * DHD;
    #pragma unroll
    for (int r = 0; r < 16; ++r) {
      int d = (r & 3) + ((r >> 2) << 3) + h4;
      orow[d] = o0[r] * inv;
      orow[d + 32] = o1[r] * inv;
    }
  } else {
    const int slot = slot_of(bh, t32, chunk);
    uint32_t w[16] __attribute__((aligned(16)));
    #pragma unroll
    for (int m = 0; m < 8; ++m) {
      w[m]     = pkbf(o0[2*m], o0[2*m+1]);
      w[8 + m] = pkbf(o1[2*m], o1[2*m+1]);
    }
    u16* op = Opart + (size_t)slot * 2048 + (size_t)lane * 32;
    #pragma unroll
    for (int i = 0; i < 4; ++i)
      *(uint4*)(op + i*8) = *(const uint4*)&w[i*4];
    if (lane < 32) lbuf[slot * 32 + lane] = l;
  }
}

// ---------------------------------------------------------------------------
// Combine split-K partials for tiles with qb>=5 (t32 20..63): plain sums.
// ---------------------------------------------------------------------------
__launch_bounds__(256)
__global__ void reduce_kernel(const u16* __restrict__ Opart,
                              const float* __restrict__ lbuf,
                              float* __restrict__ out) {
  const int t = threadIdx.x;
  const int unit = blockIdx.x * 4 + (t >> 6);   // 0..703
  const int bh = unit & 15;
  const int ti = 20 + (unit >> 4);              // t32 20..63
  const int qb = ti >> 2;
  const int nc = (2 * (qb + 1) + 9) / 10;       // 2..4
  const int lane = t & 63;
  const int lam = lane & 31;
  const int h4 = (lane >> 5) << 2;
  const int slot0 = slot_of(bh, ti, 0);

  float O[32];
  #pragma unroll
  for (int i = 0; i < 32; ++i) O[i] = 0.f;
  float L = 0.f;

  for (int c = 0; c < nc; ++c) {
    const u16* op = Opart + (size_t)(slot0 + c) * 2048 + (size_t)lane * 32;
    L += lbuf[(slot0 + c) * 32 + lam];
    #pragma unroll
    for (int i = 0; i < 4; ++i) {
      uint4 v = *(const uint4*)(op + i*8);
      uint32_t a[4] = {v.x, v.y, v.z, v.w};
      #pragma unroll
      for (int jj = 0; jj < 4; ++jj) {
        O[i*8 + 2*jj]     += bits2f((u16)(a[jj] & 0xFFFFu));
        O[i*8 + 2*jj + 1] += bits2f((u16)(a[jj] >> 16));
      }
    }
  }

  const int b = bh >> 3, hh = bh & 7;
  const float inv = 1.0f / L;
  float* orow = out + (((size_t)(hh * NB + b)) * S_LEN + (ti*32 + lam)) * DHD;
  #pragma unroll
  for (int r = 0; r < 16; ++r) {
    int d = (r & 3) + ((r >> 2) << 3) + h4;
    orow[d] = O[r] * inv;
    orow[d + 32] = O[16 + r] * inv;
  }
}

extern "C" void kernel_launch(void* const* d_in, const int* in_sizes, int n_in,
                              void* d_out, int out_size, void* d_ws, size_t ws_size,
                              hipStream_t stream) {
  const float* q = (const float*)d_in[0];
  const float* k = (const float*)d_in[1];
  const float* v = (const float*)d_in[2];
  const float* W = (const float*)d_in[3];
  const float* b = (const float*)d_in[4];

  const size_t elems = (size_t)NB * NH * S_LEN * DHD;  // 2,097,152
  u16* Qw = (u16*)d_ws;
  u16* Kw = Qw + elems;
  u16* Vt64 = Kw + elems;
  u16* Opart = Vt64 + elems;                           // 1856 slots * 4 KiB = 7.25 MiB
  float* lbuf = (float*)(Opart + (size_t)1856 * 2048); // 232 KiB

  proj_kernel<<<dim3(768), dim3(256), 0, stream>>>(q, k, v, W, b, Qw, Kw, Vt64);

  attn_kernel<<<dim3(544), dim3(256), 0, stream>>>(Qw, Kw, Vt64, Opart, lbuf, (float*)d_out);

  reduce_kernel<<<dim3(176), dim3(256), 0, stream>>>(Opart, lbuf, (float*)d_out);
}